// Round 1
// baseline (1344.649 us; speedup 1.0000x reference)
//
#include <hip/hip_runtime.h>

#define IN_F 2048
#define OUT_F 4096
#define BATCH_N 131072

// d_ws float layout:
//   [0, 64*IN_F)           partial column sums of weight (64 row-chunks)
//   [64*IN_F, 64*IN_F+IN_F) final w_sum
//   [64*IN_F+IN_F]          b_sum
#define WS_PARTIAL 0
#define WS_WSUM (64 * IN_F)
#define WS_BSUM (64 * IN_F + IN_F)

// ---------------------------------------------------------------------------
// Stage 1: partial column sums of weight (float4 over columns), + bias sum.
// grid = (2, 65). y<64: row-chunk of 64 rows, x selects 1024-column half.
// y==64 && x==0: reduce bias (4096 floats) to a scalar.
// ---------------------------------------------------------------------------
__global__ __launch_bounds__(256) void k_partial(const float* __restrict__ w,
                                                 const float* __restrict__ bias,
                                                 float* __restrict__ ws) {
    if (blockIdx.y == 64) {
        if (blockIdx.x != 0) return;
        int tid = threadIdx.x;
        float s = 0.f;
        #pragma unroll
        for (int i = 0; i < OUT_F / 256; ++i) s += bias[i * 256 + tid];
        #pragma unroll
        for (int off = 32; off; off >>= 1) s += __shfl_down(s, off, 64);
        __shared__ float red[4];
        if ((tid & 63) == 0) red[tid >> 6] = s;
        __syncthreads();
        if (tid == 0) ws[WS_BSUM] = red[0] + red[1] + red[2] + red[3];
        return;
    }
    const int col4 = blockIdx.x * 1024 + threadIdx.x * 4;   // 4 consecutive cols
    const int r0 = blockIdx.y * 64;
    const float* p = w + (size_t)r0 * IN_F + col4;
    float4 acc = make_float4(0.f, 0.f, 0.f, 0.f);
    #pragma unroll 8
    for (int r = 0; r < 64; ++r) {
        float4 v = *(const float4*)(p + (size_t)r * IN_F);
        acc.x += v.x; acc.y += v.y; acc.z += v.z; acc.w += v.w;
    }
    *(float4*)(ws + WS_PARTIAL + blockIdx.y * IN_F + col4) = acc;
}

// ---------------------------------------------------------------------------
// Stage 2: reduce 64 partials per column -> w_sum. grid = (2), 256 thr.
// ---------------------------------------------------------------------------
__global__ __launch_bounds__(256) void k_finalize(float* __restrict__ ws) {
    const int col4 = blockIdx.x * 1024 + threadIdx.x * 4;
    float4 acc = make_float4(0.f, 0.f, 0.f, 0.f);
    #pragma unroll 8
    for (int c = 0; c < 64; ++c) {
        float4 v = *(const float4*)(ws + WS_PARTIAL + c * IN_F + col4);
        acc.x += v.x; acc.y += v.y; acc.z += v.z; acc.w += v.w;
    }
    *(float4*)(ws + WS_WSUM + col4) = acc;
}

// ---------------------------------------------------------------------------
// Stage 3: out[row] = dot(x[row,:], w_sum) + b_sum. One wave per row,
// grid-stride. Lane l holds w_sum[t*256 + l*4 .. +3] for t=0..7 in registers.
// Per row: 8 coalesced float4 loads (1 KiB per wave per instr).
// ---------------------------------------------------------------------------
__global__ __launch_bounds__(256) void k_main(const float* __restrict__ x,
                                              const float* __restrict__ ws,
                                              float* __restrict__ out,
                                              int nwaves) {
    const int lane = threadIdx.x & 63;
    const int wave = (int)((blockIdx.x * blockDim.x + threadIdx.x) >> 6);

    // Hoist w_sum fragment into registers (8 KiB shared across all waves -> L2 hit)
    float4 wf[8];
    #pragma unroll
    for (int t = 0; t < 8; ++t)
        wf[t] = *(const float4*)(ws + WS_WSUM + t * 256 + lane * 4);
    const float bsum = ws[WS_BSUM];

    for (int row = wave; row < BATCH_N; row += nwaves) {
        const float4* xp = (const float4*)(x + (size_t)row * IN_F) + lane;
        float4 acc = make_float4(0.f, 0.f, 0.f, 0.f);
        #pragma unroll
        for (int t = 0; t < 8; ++t) {
            float4 xv = xp[t * 64];
            acc.x = fmaf(xv.x, wf[t].x, acc.x);
            acc.y = fmaf(xv.y, wf[t].y, acc.y);
            acc.z = fmaf(xv.z, wf[t].z, acc.z);
            acc.w = fmaf(xv.w, wf[t].w, acc.w);
        }
        float s = (acc.x + acc.y) + (acc.z + acc.w);
        #pragma unroll
        for (int off = 32; off; off >>= 1) s += __shfl_xor(s, off, 64);
        if (lane == 0) out[row] = s + bsum;
    }
}

extern "C" void kernel_launch(void* const* d_in, const int* in_sizes, int n_in,
                              void* d_out, int out_size, void* d_ws, size_t ws_size,
                              hipStream_t stream) {
    const float* x = (const float*)d_in[0];       // (131072, 2048)
    const float* w = (const float*)d_in[1];       // (4096, 2048)
    const float* bias = (const float*)d_in[2];    // (4096,)
    float* out = (float*)d_out;                   // (131072,)
    float* ws = (float*)d_ws;

    // Stage 1: weight partial column sums + bias sum
    k_partial<<<dim3(2, 65), 256, 0, stream>>>(w, bias, ws);
    // Stage 2: finalize w_sum
    k_finalize<<<dim3(2), 256, 0, stream>>>(ws);
    // Stage 3: matvec
    const int blocks = 8192;                      // 32768 waves -> 4 rows/wave
    const int nwaves = blocks * 256 / 64;
    k_main<<<dim3(blocks), 256, 0, stream>>>(x, ws, out, nwaves);
}